// Round 1
// baseline (297.734 us; speedup 1.0000x reference)
//
#include <hip/hip_runtime.h>
#include <hip/hip_bf16.h>
#include <stdint.h>

// ---------- types ----------
typedef __bf16 bf16_t;
typedef bf16_t bf16x4 __attribute__((ext_vector_type(4)));
typedef bf16_t bf16x8 __attribute__((ext_vector_type(8)));
typedef float  f32x4  __attribute__((ext_vector_type(4)));

#define MFMA16(a, b, c) __builtin_amdgcn_mfma_f32_16x16x32_bf16((a), (b), (c), 0, 0, 0)

static __device__ __forceinline__ unsigned short f2bf(float f) {
    __hip_bfloat16 h = __float2bfloat16(f);
    return __builtin_bit_cast(unsigned short, h);
}

static __device__ __forceinline__ void gld_lds16(const void* g, void* l) {
    __builtin_amdgcn_global_load_lds(
        (const __attribute__((address_space(1))) uint32_t*)g,
        (__attribute__((address_space(3))) uint32_t*)l, 16, 0, 0);
}

// ---------- problem constants ----------
#define TT     2048
#define DM     1024
#define NH     16
#define HD     64
#define MROWS  4096   // B*T

// ---------- cast fp32 -> bf16, 4 elems/thread ----------
__global__ __launch_bounds__(256) void cast_f32_bf16(const float* __restrict__ src,
                                                     unsigned short* __restrict__ dst, int n4) {
    int i = blockIdx.x * 256 + threadIdx.x;
    if (i >= n4) return;
    float4 v = reinterpret_cast<const float4*>(src)[i];
    ushort4 o;
    o.x = f2bf(v.x); o.y = f2bf(v.y); o.z = f2bf(v.z); o.w = f2bf(v.w);
    reinterpret_cast<ushort4*>(dst)[i] = o;
}

// ---------- GEMM: out[m][n] = sum_k A[m][k] * W[n][k]   (both bf16 row-major, K=1024)
// 128x128 tile, BK=32, 4 waves (2x2 quadrants of 64x64), m97 structure.
// MODE 0: QKV epilogue (scatter to q/k/v bf16, V transposed). MODE 1: fp32 out.
template <int MODE>
__global__ __launch_bounds__(256) void gemm_bt(const unsigned short* __restrict__ A,
                                               const unsigned short* __restrict__ W,
                                               float* __restrict__ out, int N,
                                               unsigned short* __restrict__ qp,
                                               unsigned short* __restrict__ kp,
                                               unsigned short* __restrict__ vp) {
    __shared__ unsigned short lA[128 * 32];
    __shared__ unsigned short lB[128 * 32];

    const int tid = threadIdx.x;
    const int l = tid & 63;
    const int w = tid >> 6;
    const int r = l & 15;
    const int g = l >> 4;
    const int wr = w >> 1, wc = w & 1;
    const int m0 = blockIdx.x * 128, n0 = blockIdx.y * 128;

    f32x4 acc[4][4];
#pragma unroll
    for (int i = 0; i < 4; i++)
#pragma unroll
        for (int j = 0; j < 4; j++) acc[i][j] = (f32x4){0.f, 0.f, 0.f, 0.f};

    // staging: 512 chunks of 16B per tile; thread handles chunk tid and tid+256
    const int c0 = tid, c1 = tid + 256;
    const int row0 = c0 >> 2, col0 = (c0 & 3) * 8;
    const int row1 = c1 >> 2, col1 = (c1 & 3) * 8;
    const unsigned short* a0 = A + (m0 + row0) * 1024 + col0;
    const unsigned short* a1 = A + (m0 + row1) * 1024 + col1;
    const unsigned short* b0 = W + (n0 + row0) * 1024 + col0;
    const unsigned short* b1 = W + (n0 + row1) * 1024 + col1;
    unsigned short* la0 = lA + c0 * 8;
    unsigned short* la1 = lA + c1 * 8;
    unsigned short* lb0 = lB + c0 * 8;
    unsigned short* lb1 = lB + c1 * 8;

    for (int k0 = 0; k0 < 1024; k0 += 32) {
        gld_lds16(a0 + k0, la0);
        gld_lds16(a1 + k0, la1);
        gld_lds16(b0 + k0, lb0);
        gld_lds16(b1 + k0, lb1);
        __syncthreads();

        bf16x8 af[4], bfr[4];
#pragma unroll
        for (int i = 0; i < 4; i++)
            af[i] = *reinterpret_cast<const bf16x8*>(lA + (wr * 64 + i * 16 + r) * 32 + g * 8);
#pragma unroll
        for (int j = 0; j < 4; j++)
            bfr[j] = *reinterpret_cast<const bf16x8*>(lB + (wc * 64 + j * 16 + r) * 32 + g * 8);
#pragma unroll
        for (int i = 0; i < 4; i++)
#pragma unroll
            for (int j = 0; j < 4; j++) acc[i][j] = MFMA16(af[i], bfr[j], acc[i][j]);
        __syncthreads();
    }

    // epilogue: C/D layout col = lane&15, row = (lane>>4)*4 + reg  [m89-verified]
#pragma unroll
    for (int i = 0; i < 4; i++) {
#pragma unroll
        for (int j = 0; j < 4; j++) {
#pragma unroll
            for (int reg = 0; reg < 4; reg++) {
                const int mg = m0 + wr * 64 + i * 16 + g * 4 + reg;
                const int ng = n0 + wc * 64 + j * 16 + r;
                const float v = acc[i][j][reg];
                if constexpr (MODE == 1) {
                    out[mg * N + ng] = v;
                } else {
                    const int sel = ng >> 10;         // 0=Q 1=K 2=V (uniform per block)
                    const int c10 = ng & 1023;
                    const int h = c10 >> 6, d = c10 & 63;
                    const int bb = mg >> 11, t = mg & 2047;
                    const int bh = bb * NH + h;
                    if (sel == 0)      qp[(bh * TT + t) * HD + d] = f2bf(v * 0.125f);
                    else if (sel == 1) kp[(bh * TT + t) * HD + d] = f2bf(v);
                    else               vp[(bh * HD + d) * TT + t] = f2bf(v);  // transposed
                }
            }
        }
    }
}

// ---------- flash attention, causal. 4 waves x 16 q-rows, KV tiles of 64. ----------
// q: [bh][t][d] bf16 (pre-scaled by 1/8), k: [bh][t][d] bf16, v: [bh][d][t] bf16.
// out: [b][t][h*64+d] bf16
__global__ __launch_bounds__(256) void attn_kernel(const unsigned short* __restrict__ q,
                                                   const unsigned short* __restrict__ k,
                                                   const unsigned short* __restrict__ v,
                                                   unsigned short* __restrict__ o) {
    __shared__ unsigned short lK[64 * 64];
    __shared__ unsigned short lV[64 * 64];
    __shared__ unsigned short lP[4 * 16 * 64];

    const int tid = threadIdx.x;
    const int l = tid & 63;
    const int w = tid >> 6;
    const int r = l & 15;
    const int g = l >> 4;
    const int bx = blockIdx.x;   // q tile
    const int bh = blockIdx.y;   // b*16 + h
    const int q0 = bx * 64;

    const unsigned short* qbase = q + (size_t)bh * TT * HD;
    const unsigned short* kbase = k + (size_t)bh * TT * HD;
    const unsigned short* vbase = v + (size_t)bh * HD * TT;

    // Q fragments (A of QK^T): row = l&15, k = (l>>4)*8 + j
    const int qrow = q0 + w * 16 + r;
    bf16x8 aq[2];
    aq[0] = *reinterpret_cast<const bf16x8*>(qbase + qrow * HD + g * 8);
    aq[1] = *reinterpret_cast<const bf16x8*>(qbase + qrow * HD + 32 + g * 8);

    f32x4 Oacc[4];
#pragma unroll
    for (int i = 0; i < 4; i++) Oacc[i] = (f32x4){0.f, 0.f, 0.f, 0.f};
    float m_r[4] = {-1e30f, -1e30f, -1e30f, -1e30f};
    float l_r[4] = {0.f, 0.f, 0.f, 0.f};

    // staging chunk geometry: 64 rows x 128B, 512 chunks of 16B, 2 per thread
    const int cA = tid, cB = tid + 256;
    const int rowA = cA >> 3, colA = (cA & 7) * 8;
    const int rowB = cB >> 3, colB = (cB & 7) * 8;
    const int dstA = rowA * 128 + ((colA * 2) ^ ((rowA & 7) << 4));  // XOR-swizzled byte off
    const int dstB = rowB * 128 + ((colB * 2) ^ ((rowB & 7) << 4));

    unsigned short* pw = lP + w * 16 * 64;  // per-wave P region

    for (int kt = 0; kt <= bx; ++kt) {
        const int k0 = kt * 64;
        // reg-staged loads (swizzled LDS writes)
        uint4 ka = *reinterpret_cast<const uint4*>(kbase + (k0 + rowA) * HD + colA);
        uint4 kb = *reinterpret_cast<const uint4*>(kbase + (k0 + rowB) * HD + colB);
        uint4 va = *reinterpret_cast<const uint4*>(vbase + rowA * TT + k0 + colA);
        uint4 vb = *reinterpret_cast<const uint4*>(vbase + rowB * TT + k0 + colB);
        *reinterpret_cast<uint4*>((char*)lK + dstA) = ka;
        *reinterpret_cast<uint4*>((char*)lK + dstB) = kb;
        *reinterpret_cast<uint4*>((char*)lV + dstA) = va;
        *reinterpret_cast<uint4*>((char*)lV + dstB) = vb;
        __syncthreads();

        // S = Q K^T : D[q][kv], 4 n-tiles x 2 k-steps
        f32x4 s[4];
#pragma unroll
        for (int j = 0; j < 4; j++) s[j] = (f32x4){0.f, 0.f, 0.f, 0.f};
#pragma unroll
        for (int j = 0; j < 4; j++) {
#pragma unroll
            for (int ks = 0; ks < 2; ks++) {
                const int row = j * 16 + r;  // kv row in tile
                bf16x8 bk = *reinterpret_cast<const bf16x8*>(
                    (char*)lK + row * 128 + (((ks * 32 + g * 8) * 2) ^ ((row & 7) << 4)));
                s[j] = MFMA16(aq[ks], bk, s[j]);
            }
        }

        // causal mask (diagonal tile only)
        if (k0 + 63 > q0 + w * 16) {
#pragma unroll
            for (int j = 0; j < 4; j++)
#pragma unroll
                for (int reg = 0; reg < 4; reg++) {
                    const int kvg = k0 + j * 16 + r;
                    const int qg = q0 + w * 16 + g * 4 + reg;
                    if (kvg > qg) s[j][reg] = -1e30f;
                }
        }

        // online softmax per row (reg r4 -> row g*4+r4); reduce across 16-lane group
        float ptile[4][4];
#pragma unroll
        for (int reg = 0; reg < 4; reg++) {
            float mt = fmaxf(fmaxf(s[0][reg], s[1][reg]), fmaxf(s[2][reg], s[3][reg]));
#pragma unroll
            for (int off = 1; off < 16; off <<= 1) mt = fmaxf(mt, __shfl_xor(mt, off));
            const float mnew = fmaxf(m_r[reg], mt);
            const float corr = __expf(m_r[reg] - mnew);
            float sum = 0.f;
#pragma unroll
            for (int j = 0; j < 4; j++) {
                const float p = __expf(s[j][reg] - mnew);
                ptile[j][reg] = p;
                sum += p;
            }
#pragma unroll
            for (int off = 1; off < 16; off <<= 1) sum += __shfl_xor(sum, off);
            l_r[reg] = l_r[reg] * corr + sum;
            m_r[reg] = mnew;
#pragma unroll
            for (int jd = 0; jd < 4; jd++) Oacc[jd][reg] *= corr;
        }

        // P -> per-wave LDS (bf16, swizzled); no barrier needed (wave-private)
#pragma unroll
        for (int j = 0; j < 4; j++)
#pragma unroll
            for (int reg = 0; reg < 4; reg++) {
                const int row = g * 4 + reg;
                const int byte = row * 128 + (((j * 16 + r) * 2) ^ ((row & 7) << 4));
                *reinterpret_cast<unsigned short*>((char*)pw + byte) = f2bf(ptile[j][reg]);
            }

        // O += P V : A = P[16x64], B = V[kv][d] read from V^T lds [d][t]
        bf16x8 pf[2];
#pragma unroll
        for (int ks = 0; ks < 2; ks++)
            pf[ks] = *reinterpret_cast<const bf16x8*>(
                (char*)pw + r * 128 + (((ks * 32 + g * 8) * 2) ^ ((r & 7) << 4)));
#pragma unroll
        for (int jd = 0; jd < 4; jd++) {
#pragma unroll
            for (int ks = 0; ks < 2; ks++) {
                const int vrow = jd * 16 + r;  // d row in V^T tile
                bf16x8 vf = *reinterpret_cast<const bf16x8*>(
                    (char*)lV + vrow * 128 + (((ks * 32 + g * 8) * 2) ^ ((vrow & 7) << 4)));
                Oacc[jd] = MFMA16(pf[ks], vf, Oacc[jd]);
            }
        }
        __syncthreads();
    }

    // normalize + store: out[b][t][h*64+d] bf16
    const int b_ = bh >> 4, h_ = bh & 15;
#pragma unroll
    for (int reg = 0; reg < 4; reg++) {
        const int qg = q0 + w * 16 + g * 4 + reg;
        const float inv = 1.f / l_r[reg];
#pragma unroll
        for (int jd = 0; jd < 4; jd++) {
            const int d_ = jd * 16 + r;
            o[((size_t)b_ * TT + qg) * DM + h_ * HD + d_] = f2bf(Oacc[jd][reg] * inv);
        }
    }
}

// ---------- launch ----------
extern "C" void kernel_launch(void* const* d_in, const int* in_sizes, int n_in,
                              void* d_out, int out_size, void* d_ws, size_t ws_size,
                              hipStream_t stream) {
    const float* x  = (const float*)d_in[0];
    const float* Wq = (const float*)d_in[1];
    const float* Wk = (const float*)d_in[2];
    const float* Wv = (const float*)d_in[3];
    const float* Wo = (const float*)d_in[4];
    // d_in[5] = attn_mask (causal; implemented analytically)

    char* ws = (char*)d_ws;
    unsigned short* xb   = (unsigned short*)(ws);                    //  8 MB  [4096][1024]
    unsigned short* wqkv = (unsigned short*)(ws + (8u  << 20));      //  6 MB  [3072][1024]
    unsigned short* wo   = (unsigned short*)(ws + (14u << 20));      //  2 MB  [1024][1024]
    unsigned short* qb   = (unsigned short*)(ws + (16u << 20));      //  8 MB  [32][2048][64]
    unsigned short* kb   = (unsigned short*)(ws + (24u << 20));      //  8 MB  [32][2048][64]
    unsigned short* vb   = (unsigned short*)(ws + (32u << 20));      //  8 MB  [32][64][2048]
    unsigned short* ab   = (unsigned short*)(ws + (40u << 20));      //  8 MB  [4096][1024]
    float* outp = (float*)d_out;

    cast_f32_bf16<<<4096, 256, 0, stream>>>(x, xb, 1048576);
    cast_f32_bf16<<<1024, 256, 0, stream>>>(Wq, wqkv, 262144);
    cast_f32_bf16<<<1024, 256, 0, stream>>>(Wk, wqkv + (1u << 20), 262144);
    cast_f32_bf16<<<1024, 256, 0, stream>>>(Wv, wqkv + (2u << 20), 262144);
    cast_f32_bf16<<<1024, 256, 0, stream>>>(Wo, wo, 262144);

    gemm_bt<0><<<dim3(32, 24), 256, 0, stream>>>(xb, wqkv, nullptr, 3072, qb, kb, vb);
    attn_kernel<<<dim3(32, 32), 256, 0, stream>>>(qb, kb, vb, ab);
    gemm_bt<1><<<dim3(32, 8), 256, 0, stream>>>(ab, wo, outp, 1024, nullptr, nullptr, nullptr);
}

// Round 2
// 233.197 us; speedup vs baseline: 1.2767x; 1.2767x over previous
//
#include <hip/hip_runtime.h>
#include <hip/hip_bf16.h>
#include <stdint.h>

// ---------- types ----------
typedef __bf16 bf16_t;
typedef bf16_t bf16x4 __attribute__((ext_vector_type(4)));
typedef bf16_t bf16x8 __attribute__((ext_vector_type(8)));
typedef float  f32x4  __attribute__((ext_vector_type(4)));
typedef float  f32x16 __attribute__((ext_vector_type(16)));

#define MFMA16(a, b, c) __builtin_amdgcn_mfma_f32_16x16x32_bf16((a), (b), (c), 0, 0, 0)
#define MFMA32(a, b, c) __builtin_amdgcn_mfma_f32_32x32x16_bf16((a), (b), (c), 0, 0, 0)

static __device__ __forceinline__ unsigned short f2bf(float f) {
    __hip_bfloat16 h = __float2bfloat16(f);
    return __builtin_bit_cast(unsigned short, h);
}
static __device__ __forceinline__ unsigned int pk2(float a, float b) {
    return ((unsigned int)f2bf(b) << 16) | (unsigned int)f2bf(a);
}

static __device__ __forceinline__ void gld_lds16(const void* g, void* l) {
    __builtin_amdgcn_global_load_lds(
        (const __attribute__((address_space(1))) uint32_t*)g,
        (__attribute__((address_space(3))) uint32_t*)l, 16, 0, 0);
}

// ---------- problem constants ----------
#define TT     2048
#define DM     1024
#define NH     16
#define HD     64
#define MROWS  4096   // B*T

// ---------- cast fp32 -> bf16, 4 elems/thread ----------
__global__ __launch_bounds__(256) void cast_f32_bf16(const float* __restrict__ src,
                                                     unsigned short* __restrict__ dst, int n4) {
    int i = blockIdx.x * 256 + threadIdx.x;
    if (i >= n4) return;
    float4 v = reinterpret_cast<const float4*>(src)[i];
    ushort4 o;
    o.x = f2bf(v.x); o.y = f2bf(v.y); o.z = f2bf(v.z); o.w = f2bf(v.w);
    reinterpret_cast<ushort4*>(dst)[i] = o;
}

// ---------- GEMM: out[m][n] = sum_k A[m][k] * W[n][k]   (both bf16 row-major, K=1024)
// 128x128 tile, BK=32, 4 waves (2x2 quadrants of 64x64), m97 structure.
// MODE 0: QKV epilogue (scatter to q/k/v bf16, V transposed). MODE 1: fp32 out.
template <int MODE>
__global__ __launch_bounds__(256) void gemm_bt(const unsigned short* __restrict__ A,
                                               const unsigned short* __restrict__ W,
                                               float* __restrict__ out, int N,
                                               unsigned short* __restrict__ qp,
                                               unsigned short* __restrict__ kp,
                                               unsigned short* __restrict__ vp) {
    __shared__ unsigned short lA[128 * 32];
    __shared__ unsigned short lB[128 * 32];

    const int tid = threadIdx.x;
    const int l = tid & 63;
    const int w = tid >> 6;
    const int r = l & 15;
    const int g = l >> 4;
    const int wr = w >> 1, wc = w & 1;
    const int m0 = blockIdx.x * 128, n0 = blockIdx.y * 128;

    f32x4 acc[4][4];
#pragma unroll
    for (int i = 0; i < 4; i++)
#pragma unroll
        for (int j = 0; j < 4; j++) acc[i][j] = (f32x4){0.f, 0.f, 0.f, 0.f};

    const int c0 = tid, c1 = tid + 256;
    const int row0 = c0 >> 2, col0 = (c0 & 3) * 8;
    const int row1 = c1 >> 2, col1 = (c1 & 3) * 8;
    const unsigned short* a0 = A + (m0 + row0) * 1024 + col0;
    const unsigned short* a1 = A + (m0 + row1) * 1024 + col1;
    const unsigned short* b0 = W + (n0 + row0) * 1024 + col0;
    const unsigned short* b1 = W + (n0 + row1) * 1024 + col1;
    unsigned short* la0 = lA + c0 * 8;
    unsigned short* la1 = lA + c1 * 8;
    unsigned short* lb0 = lB + c0 * 8;
    unsigned short* lb1 = lB + c1 * 8;

    for (int k0 = 0; k0 < 1024; k0 += 32) {
        gld_lds16(a0 + k0, la0);
        gld_lds16(a1 + k0, la1);
        gld_lds16(b0 + k0, lb0);
        gld_lds16(b1 + k0, lb1);
        __syncthreads();

        bf16x8 af[4], bfr[4];
#pragma unroll
        for (int i = 0; i < 4; i++)
            af[i] = *reinterpret_cast<const bf16x8*>(lA + (wr * 64 + i * 16 + r) * 32 + g * 8);
#pragma unroll
        for (int j = 0; j < 4; j++)
            bfr[j] = *reinterpret_cast<const bf16x8*>(lB + (wc * 64 + j * 16 + r) * 32 + g * 8);
#pragma unroll
        for (int i = 0; i < 4; i++)
#pragma unroll
            for (int j = 0; j < 4; j++) acc[i][j] = MFMA16(af[i], bfr[j], acc[i][j]);
        __syncthreads();
    }

    // epilogue: C/D layout col = lane&15, row = (lane>>4)*4 + reg
#pragma unroll
    for (int i = 0; i < 4; i++) {
#pragma unroll
        for (int j = 0; j < 4; j++) {
#pragma unroll
            for (int reg = 0; reg < 4; reg++) {
                const int mg = m0 + wr * 64 + i * 16 + g * 4 + reg;
                const int ng = n0 + wc * 64 + j * 16 + r;
                const float v = acc[i][j][reg];
                if constexpr (MODE == 1) {
                    out[mg * N + ng] = v;
                } else {
                    const int sel = ng >> 10;         // 0=Q 1=K 2=V
                    const int c10 = ng & 1023;
                    const int h = c10 >> 6, d = c10 & 63;
                    const int bb = mg >> 11, t = mg & 2047;
                    const int bh = bb * NH + h;
                    if (sel == 0)      qp[(bh * TT + t) * HD + d] = f2bf(v * 0.125f);
                    else if (sel == 1) kp[(bh * TT + t) * HD + d] = f2bf(v);
                    else               vp[(bh * HD + d) * TT + t] = f2bf(v);  // transposed
                }
            }
        }
    }
}

// ---------- flash attention, causal, swapped-QK^T structure ----------
// 4 waves x 32 q-rows (Q-tile 128), KV tile 64. q:[bh][t][d] (pre-scaled 1/8),
// k:[bh][t][d], v:[bh][d][t] (transposed). out: [b][t][h*64+d] bf16.
// S^T = mfma(K,Q): lane c=l&31 owns q-row q0w+c; softmax is lane-local.
// O^T = mfma(V^T, P^T): rescale/normalize are lane-scalars.
__global__ __launch_bounds__(256) void attn_kernel(const unsigned short* __restrict__ q,
                                                   const unsigned short* __restrict__ k,
                                                   const unsigned short* __restrict__ v,
                                                   unsigned short* __restrict__ o) {
    __shared__ unsigned short lK[64 * 64];
    __shared__ unsigned short lV[64 * 64];

    const int tid = threadIdx.x;
    const int l   = tid & 63;
    const int w   = tid >> 6;
    const int c   = l & 31;
    const int hi  = l >> 5;

    // causal load-balance: blocks id and id+256 get complementary q-tiles
    const int id   = blockIdx.x;
    const int half = id >> 8;
    const int sub  = id & 255;
    const int bh   = sub >> 3;
    const int j8   = sub & 7;
    const int qt   = half ? (15 - j8) : j8;
    const int q0w  = qt * 128 + w * 32;
    const int nkt  = 2 * qt + 2;

    const unsigned short* qbase = q + (size_t)bh * TT * HD;
    const unsigned short* kbase = k + (size_t)bh * TT * HD;
    const unsigned short* vbase = v + (size_t)bh * HD * TT;

    // Q B-fragments: row(q) = q0w + c, k(d) = ks*16 + hi*8 + e
    bf16x8 qf[4];
#pragma unroll
    for (int ks = 0; ks < 4; ++ks)
        qf[ks] = *reinterpret_cast<const bf16x8*>(qbase + (q0w + c) * HD + ks * 16 + hi * 8);

    f32x16 Oacc[2];
#pragma unroll
    for (int jd = 0; jd < 2; ++jd)
#pragma unroll
        for (int e = 0; e < 16; ++e) Oacc[jd][e] = 0.f;
    float m_r = -1e30f, l_r = 0.f;

    // staging: 64 rows x 128B per tile, 512 16B-chunks, 2 per thread per tile
    const int cA = tid, cB = tid + 256;
    const int rA = cA >> 3, colA = (cA & 7) * 8;
    const int rB = cB >> 3, colB = (cB & 7) * 8;
    const int dstA = rA * 128 + ((colA * 2) ^ ((rA & 7) << 4));  // XOR-swizzled
    const int dstB = rB * 128 + ((colB & 7) == (cB & 7) ? ((colB * 2) ^ ((rB & 7) << 4)) : 0);
    // (colB expression kept simple below)

    uint4 ka, kb, va, vb;
    ka = *reinterpret_cast<const uint4*>(kbase + rA * HD + colA);
    kb = *reinterpret_cast<const uint4*>(kbase + rB * HD + colB);
    va = *reinterpret_cast<const uint4*>(vbase + rA * TT + colA);
    vb = *reinterpret_cast<const uint4*>(vbase + rB * TT + colB);

    const int dstB2 = rB * 128 + ((colB * 2) ^ ((rB & 7) << 4));

    for (int kt = 0; kt < nkt; ++kt) {
        const int k0 = kt * 64;
        __syncthreads();  // previous tile fully consumed
        *reinterpret_cast<uint4*>((char*)lK + dstA)  = ka;
        *reinterpret_cast<uint4*>((char*)lK + dstB2) = kb;
        *reinterpret_cast<uint4*>((char*)lV + dstA)  = va;
        *reinterpret_cast<uint4*>((char*)lV + dstB2) = vb;
        __syncthreads();  // tile ready
        if (kt + 1 < nkt) {  // async prefetch next tile into regs (T14)
            const int kn = k0 + 64;
            ka = *reinterpret_cast<const uint4*>(kbase + (kn + rA) * HD + colA);
            kb = *reinterpret_cast<const uint4*>(kbase + (kn + rB) * HD + colB);
            va = *reinterpret_cast<const uint4*>(vbase + rA * TT + kn + colA);
            vb = *reinterpret_cast<const uint4*>(vbase + rB * TT + kn + colB);
        }
        if (k0 > q0w + 31) continue;  // fully masked for this wave (wave-uniform)

        // S^T[kv][q] = K Q^T : 2 kv-subtiles x 4 k-steps
        f32x16 s[2];
#pragma unroll
        for (int j = 0; j < 2; ++j) {
#pragma unroll
            for (int e = 0; e < 16; ++e) s[j][e] = 0.f;
#pragma unroll
            for (int ks = 0; ks < 4; ++ks) {
                const int row = j * 32 + c;
                bf16x8 kf = *reinterpret_cast<const bf16x8*>(
                    (char*)lK + row * 128 + (((ks * 16 + hi * 8) * 2) ^ ((row & 7) << 4)));
                s[j] = MFMA32(kf, qf[ks], s[j]);
            }
        }

        // causal mask: kv = k0 + j*32 + (e&3)+8*(e>>2)+4*hi ; q = q0w + c
        if (k0 + 63 > q0w) {
            const int qg = q0w + c;
#pragma unroll
            for (int j = 0; j < 2; ++j)
#pragma unroll
                for (int e = 0; e < 16; ++e) {
                    const int kv = k0 + j * 32 + (e & 3) + 8 * (e >> 2) + 4 * hi;
                    if (kv > qg) s[j][e] = -1e30f;
                }
        }

        // online softmax — lane-local (row q = q0w + c)
        float mx = s[0][0];
#pragma unroll
        for (int e = 1; e < 16; ++e) mx = fmaxf(mx, s[0][e]);
#pragma unroll
        for (int e = 0; e < 16; ++e) mx = fmaxf(mx, s[1][e]);
        mx = fmaxf(mx, __shfl_xor(mx, 32));
        const float mnew = fmaxf(m_r, mx);
        const float corr = __expf(m_r - mnew);
        float sum = 0.f;
#pragma unroll
        for (int j = 0; j < 2; ++j)
#pragma unroll
            for (int e = 0; e < 16; ++e) {
                const float p = __expf(s[j][e] - mnew);
                s[j][e] = p;
                sum += p;
            }
        sum += __shfl_xor(sum, 32);
        l_r = l_r * corr + sum;
        m_r = mnew;
#pragma unroll
        for (int jd = 0; jd < 2; ++jd)
#pragma unroll
            for (int e = 0; e < 16; ++e) Oacc[jd][e] *= corr;

        // P^T regs -> PA fragments (in-register, one cross-half shfl pair per ks)
        // pa[ks][el] = P[q=c][kv = ks*16 + 8*hi + el]; el0-3 from hi=0 lane, el4-7 from hi=1.
        bf16x8 pa[4];
#pragma unroll
        for (int ks = 0; ks < 4; ++ks) {
            const int j = ks >> 1;
            const int base = (ks & 1) * 8;
            const unsigned int pA0 = pk2(s[j][base + 0], s[j][base + 1]);
            const unsigned int pA1 = pk2(s[j][base + 2], s[j][base + 3]);
            const unsigned int pB0 = pk2(s[j][base + 4], s[j][base + 5]);
            const unsigned int pB1 = pk2(s[j][base + 6], s[j][base + 7]);
            // mine (serves dest hi_d == hi): regs base+4*hi ; partner's need: base+4*(1-hi)
            const unsigned int m0 = hi ? pB0 : pA0;
            const unsigned int m1 = hi ? pB1 : pA1;
            const unsigned int o0 = hi ? pA0 : pB0;
            const unsigned int o1 = hi ? pA1 : pB1;
            const unsigned int r0 = __shfl_xor(o0, 32);
            const unsigned int r1 = __shfl_xor(o1, 32);
            uint4 u;
            u.x = hi ? r0 : m0;
            u.y = hi ? r1 : m1;
            u.z = hi ? m0 : r0;
            u.w = hi ? m1 : r1;
            pa[ks] = __builtin_bit_cast(bf16x8, u);
        }

        // O^T[d][q] += V^T P^T : A = V^T (rows d), B = pa
#pragma unroll
        for (int jd = 0; jd < 2; ++jd) {
#pragma unroll
            for (int ks = 0; ks < 4; ++ks) {
                const int row = jd * 32 + c;
                bf16x8 vf = *reinterpret_cast<const bf16x8*>(
                    (char*)lV + row * 128 + (((ks * 16 + hi * 8) * 2) ^ ((row & 7) << 4)));
                Oacc[jd] = MFMA32(vf, pa[ks], Oacc[jd]);
            }
        }
    }

    // epilogue: lane c holds q-row q0w+c ; d = jd*32 + (e&3)+8*(e>>2)+4*hi
    const int b_ = bh >> 4, h_ = bh & 15;
    const float inv = 1.f / l_r;
    const int qg = q0w + c;
    unsigned short* orow = o + ((size_t)b_ * TT + qg) * DM + h_ * HD;
#pragma unroll
    for (int jd = 0; jd < 2; ++jd)
#pragma unroll
        for (int ep = 0; ep < 8; ++ep) {
            const int e0 = ep * 2;
            const int d0 = jd * 32 + (e0 & 3) + 8 * (e0 >> 2) + 4 * hi;
            const unsigned int pkv = pk2(Oacc[jd][e0] * inv, Oacc[jd][e0 + 1] * inv);
            *reinterpret_cast<unsigned int*>(orow + d0) = pkv;
        }
}

// ---------- launch ----------
extern "C" void kernel_launch(void* const* d_in, const int* in_sizes, int n_in,
                              void* d_out, int out_size, void* d_ws, size_t ws_size,
                              hipStream_t stream) {
    const float* x  = (const float*)d_in[0];
    const float* Wq = (const float*)d_in[1];
    const float* Wk = (const float*)d_in[2];
    const float* Wv = (const float*)d_in[3];
    const float* Wo = (const float*)d_in[4];
    // d_in[5] = attn_mask (causal; implemented analytically)

    char* ws = (char*)d_ws;
    unsigned short* xb   = (unsigned short*)(ws);                    //  8 MB  [4096][1024]
    unsigned short* wqkv = (unsigned short*)(ws + (8u  << 20));      //  6 MB  [3072][1024]
    unsigned short* wo   = (unsigned short*)(ws + (14u << 20));      //  2 MB  [1024][1024]
    unsigned short* qb   = (unsigned short*)(ws + (16u << 20));      //  8 MB  [32][2048][64]
    unsigned short* kb   = (unsigned short*)(ws + (24u << 20));      //  8 MB  [32][2048][64]
    unsigned short* vb   = (unsigned short*)(ws + (32u << 20));      //  8 MB  [32][64][2048]
    unsigned short* ab   = (unsigned short*)(ws + (40u << 20));      //  8 MB  [4096][1024]
    float* outp = (float*)d_out;

    cast_f32_bf16<<<4096, 256, 0, stream>>>(x, xb, 1048576);
    cast_f32_bf16<<<1024, 256, 0, stream>>>(Wq, wqkv, 262144);
    cast_f32_bf16<<<1024, 256, 0, stream>>>(Wk, wqkv + (1u << 20), 262144);
    cast_f32_bf16<<<1024, 256, 0, stream>>>(Wv, wqkv + (2u << 20), 262144);
    cast_f32_bf16<<<1024, 256, 0, stream>>>(Wo, wo, 262144);

    gemm_bt<0><<<dim3(32, 24), 256, 0, stream>>>(xb, wqkv, nullptr, 3072, qb, kb, vb);
    attn_kernel<<<512, 256, 0, stream>>>(qb, kb, vb, ab);
    gemm_bt<1><<<dim3(32, 8), 256, 0, stream>>>(ab, wo, outp, 1024, nullptr, nullptr, nullptr);
}